// Round 1
// baseline (305.800 us; speedup 1.0000x reference)
//
#include <hip/hip_runtime.h>

typedef __bf16 bf16x8 __attribute__((ext_vector_type(8)));
typedef float f32x4 __attribute__((ext_vector_type(4)));
typedef unsigned short ushort8 __attribute__((ext_vector_type(8)));

__device__ __forceinline__ unsigned short f2b(float f) {
    unsigned int u = __float_as_uint(f);
    return (unsigned short)((u + 0x7fffu + ((u >> 16) & 1u)) >> 16);  // RNE
}

// ---------------------------------------------------------------------------
// Prep: fold W_nl into W_out, emit bf16 W' in MFMA B-fragment order, and the
// fused bias b'[o] = b_out[o] + sum_f b_nl[f]*W_out[o,f].
// Fragment layout (for mfma_f32_16x16x32_bf16): flat index
//   t = (((ct*8 + ks)*64 + lane)*8 + j)
// holds B[k = ks*32 + (lane>>4)*8 + j][n = ct*16 + (lane&15)]
// with B[f][o] = s*(W_nl[f,0]+W_nl[f,1]) * W_out[o,f].
// ---------------------------------------------------------------------------
__global__ __launch_bounds__(256) void wk_prep(
    const float* __restrict__ Wnl, const float* __restrict__ bnl,
    const float* __restrict__ Wout, const float* __restrict__ bout,
    unsigned short* __restrict__ wfrag, float* __restrict__ wbias) {
    int b = blockIdx.x, tid = threadIdx.x;
    if (b < 256) {
        int t = b * 256 + tid;
        int j = t & 7;
        int lane = (t >> 3) & 63;
        int ks = (t >> 9) & 7;
        int ct = t >> 12;                       // global col-tile 0..15
        int f = ks * 32 + ((lane >> 4) << 3) + j;
        int o = ct * 16 + (lane & 15);
        float c = 0.70710678f * (Wnl[2 * f] + Wnl[2 * f + 1]);
        wfrag[t] = f2b(c * Wout[o * 256 + f]);
    } else {
        int o = tid;
        float s = 0.f;
        #pragma unroll 8
        for (int f = 0; f < 256; ++f) s += bnl[f] * Wout[o * 256 + f];
        wbias[o] = bout[o] + s;
    }
}

// ---------------------------------------------------------------------------
// Main GEMM: M=160000 rows, K=256, N=256.  Block = 512 thr (8 waves).
// Each block: one 128-row tile x one 128-col half. LDS holds that half of W'
// (64 KB, fragment-ordered -> ds_read_b128 per MFMA).
// blockIdx.x: bit0 = col half (paired blocks share x rows -> L2/L3 reuse).
// ---------------------------------------------------------------------------
__global__ __launch_bounds__(512, 2) void wk_main(
    const float* __restrict__ x, const unsigned short* __restrict__ wfrag,
    const float* __restrict__ wbias, float* __restrict__ out) {
    const int tid  = threadIdx.x;
    const int lane = tid & 63;
    const int w    = tid >> 6;          // wave 0..7
    const int m    = lane & 15;
    const int quad = lane >> 4;

    const int half    = blockIdx.x & 1;
    const int rowTile = blockIdx.x >> 1;
    const int r0      = rowTile * 128 + w * 16;

    __shared__ bf16x8 Wlds[4096];       // 64 KB: [ct(8)][ks(8)][lane(64)] x 8 bf16

    // --- stage W' half into LDS (coalesced 16B copies) ---
    {
        int4* dst = (int4*)Wlds;
        const int4* src = (const int4*)(wfrag + half * 32768);
        #pragma unroll
        for (int i = 0; i < 8; ++i) dst[tid + i * 512] = src[tid + i * 512];
    }

    // --- load this wave's 16 rows of x (full K=256), 32 contiguous B/lane ---
    const float4* xv = (const float4*)(x + (size_t)(r0 + m) * 256);
    const int kb = quad * 2;            // quad*8 floats in float4 units
    float4 a0[8], a1[8];
    #pragma unroll
    for (int ks = 0; ks < 8; ++ks) {
        a0[ks] = xv[ks * 8 + kb];
        a1[ks] = xv[ks * 8 + kb + 1];
    }

    // --- bias for my 8 output col-tiles ---
    float bias_r[8];
    #pragma unroll
    for (int ct = 0; ct < 8; ++ct)
        bias_r[ct] = wbias[half * 128 + ct * 16 + m];

    // --- fp32 -> bf16 A fragments (A[m=lane&15][k=quad*8+j]) ---
    bf16x8 afr[8];
    #pragma unroll
    for (int ks = 0; ks < 8; ++ks) {
        ushort8 s;
        s[0] = f2b(a0[ks].x); s[1] = f2b(a0[ks].y);
        s[2] = f2b(a0[ks].z); s[3] = f2b(a0[ks].w);
        s[4] = f2b(a1[ks].x); s[5] = f2b(a1[ks].y);
        s[6] = f2b(a1[ks].z); s[7] = f2b(a1[ks].w);
        afr[ks] = __builtin_bit_cast(bf16x8, s);
    }

    __syncthreads();

    // --- 8 col-tiles x 8 K-steps of MFMA, bias-initialized accumulators ---
    #pragma unroll
    for (int ct = 0; ct < 8; ++ct) {
        f32x4 acc = {bias_r[ct], bias_r[ct], bias_r[ct], bias_r[ct]};
        #pragma unroll
        for (int ks = 0; ks < 8; ++ks) {
            acc = __builtin_amdgcn_mfma_f32_16x16x32_bf16(
                afr[ks], Wlds[(ct * 8 + ks) * 64 + lane], acc, 0, 0, 0);
        }
        // D layout: row = quad*4 + i, col = lane&15
        size_t base = (size_t)(r0 + quad * 4) * 256 + half * 128 + ct * 16 + m;
        out[base]       = acc[0];
        out[base + 256] = acc[1];
        out[base + 512] = acc[2];
        out[base + 768] = acc[3];
    }
}

extern "C" void kernel_launch(void* const* d_in, const int* in_sizes, int n_in,
                              void* d_out, int out_size, void* d_ws, size_t ws_size,
                              hipStream_t stream) {
    const float* x    = (const float*)d_in[0];   // [8,20000,256]
    const float* Wnl  = (const float*)d_in[1];   // [256,2]
    const float* bnl  = (const float*)d_in[2];   // [256]
    const float* Wout = (const float*)d_in[3];   // [256,256]
    const float* bout = (const float*)d_in[4];   // [256]

    unsigned short* wfrag = (unsigned short*)d_ws;            // 65536 bf16 = 128 KB
    float* wbias = (float*)((char*)d_ws + 131072);            // 256 f32

    wk_prep<<<257, 256, 0, stream>>>(Wnl, bnl, Wout, bout, wfrag, wbias);
    wk_main<<<2500, 512, 0, stream>>>(x, wfrag, wbias, (float*)d_out);
}

// Round 2
// 300.640 us; speedup vs baseline: 1.0172x; 1.0172x over previous
//
#include <hip/hip_runtime.h>

typedef __bf16 bf16x8 __attribute__((ext_vector_type(8)));
typedef float f32x4 __attribute__((ext_vector_type(4)));
typedef unsigned short ushort8 __attribute__((ext_vector_type(8)));

__device__ __forceinline__ unsigned short f2b(float f) {
    unsigned int u = __float_as_uint(f);
    return (unsigned short)((u + 0x7fffu + ((u >> 16) & 1u)) >> 16);  // RNE
}

// ---------------------------------------------------------------------------
// Prep: fold W_nl into W_out, emit bf16 W' in MFMA B-fragment order, and the
// fused bias b'[o] = b_out[o] + sum_f b_nl[f]*W_out[o,f].
// Fragment layout (for mfma_f32_16x16x32_bf16): flat index
//   t = (((ct*8 + ks)*64 + lane)*8 + j)
// holds B[k = ks*32 + (lane>>4)*8 + j][n = ct*16 + (lane&15)]
// with B[f][o] = s*(W_nl[f,0]+W_nl[f,1]) * W_out[o,f].
// ---------------------------------------------------------------------------
__global__ __launch_bounds__(256) void wk_prep(
    const float* __restrict__ Wnl, const float* __restrict__ bnl,
    const float* __restrict__ Wout, const float* __restrict__ bout,
    unsigned short* __restrict__ wfrag, float* __restrict__ wbias) {
    int b = blockIdx.x, tid = threadIdx.x;
    if (b < 256) {
        int t = b * 256 + tid;
        int j = t & 7;
        int lane = (t >> 3) & 63;
        int ks = (t >> 9) & 7;
        int ct = t >> 12;                       // global col-tile 0..15
        int f = ks * 32 + ((lane >> 4) << 3) + j;
        int o = ct * 16 + (lane & 15);
        float c = 0.70710678f * (Wnl[2 * f] + Wnl[2 * f + 1]);
        wfrag[t] = f2b(c * Wout[o * 256 + f]);
    } else {
        int o = tid;
        float s = 0.f;
        #pragma unroll 8
        for (int f = 0; f < 256; ++f) s += bnl[f] * Wout[o * 256 + f];
        wbias[o] = bout[o] + s;
    }
}

// ---------------------------------------------------------------------------
// Main GEMM: M=160000, K=256, N=256. Block = 512 thr (8 waves), 128 rows,
// FULL 256 cols per block -> x read from HBM exactly once.
// LDS = 64 KB, holds one 128-col half of W' at a time; halves staged
// sequentially while x lives in bf16 A-fragments (registers) throughout.
// 2 blocks/CU (LDS 128 KB, VGPR capped at 128 via launch_bounds(512,4)).
// ---------------------------------------------------------------------------
__global__ __launch_bounds__(512, 4) void wk_main(
    const float* __restrict__ x, const unsigned short* __restrict__ wfrag,
    const float* __restrict__ wbias, float* __restrict__ out) {
    const int tid  = threadIdx.x;
    const int lane = tid & 63;
    const int w    = tid >> 6;          // wave 0..7
    const int m    = lane & 15;
    const int quad = lane >> 4;
    const int r0   = blockIdx.x * 128 + w * 16;

    __shared__ bf16x8 Wlds[4096];       // 64 KB: [ct(8)][ks(8)][lane(64)] x 8 bf16

    // --- stage half 0 of W' (coalesced 16B copies, L2-resident source) ---
    {
        int4* dst = (int4*)Wlds;
        const int4* src = (const int4*)wfrag;
        #pragma unroll
        for (int i = 0; i < 8; ++i) dst[tid + i * 512] = src[tid + i * 512];
    }

    // --- load this wave's 16 rows of x (full K=256), 32 contiguous B/lane,
    //     chunked 2x to keep raw-float live range at 32 VGPRs ---
    const float4* xv = (const float4*)(x + (size_t)(r0 + m) * 256);
    bf16x8 afr[8];                      // A[m=lane&15][k = quad*8 + j], ks-major
    #pragma unroll
    for (int c = 0; c < 2; ++c) {
        float4 u[4], v[4];
        #pragma unroll
        for (int q = 0; q < 4; ++q) {
            int ks = c * 4 + q;
            u[q] = xv[ks * 8 + quad * 2];
            v[q] = xv[ks * 8 + quad * 2 + 1];
        }
        #pragma unroll
        for (int q = 0; q < 4; ++q) {
            ushort8 s;
            s[0] = f2b(u[q].x); s[1] = f2b(u[q].y);
            s[2] = f2b(u[q].z); s[3] = f2b(u[q].w);
            s[4] = f2b(v[q].x); s[5] = f2b(v[q].y);
            s[6] = f2b(v[q].z); s[7] = f2b(v[q].w);
            afr[c * 4 + q] = __builtin_bit_cast(bf16x8, s);
        }
    }

    __syncthreads();

    #pragma unroll
    for (int h = 0; h < 2; ++h) {
        if (h == 1) {
            __syncthreads();            // all waves done reading half 0
            int4* dst = (int4*)Wlds;
            const int4* src = (const int4*)(wfrag + 32768);
            #pragma unroll
            for (int i = 0; i < 8; ++i) dst[tid + i * 512] = src[tid + i * 512];
            __syncthreads();
        }
        #pragma unroll
        for (int ct = 0; ct < 8; ++ct) {
            float b = wbias[h * 128 + ct * 16 + m];
            f32x4 acc = {b, b, b, b};
            #pragma unroll
            for (int ks = 0; ks < 8; ++ks) {
                acc = __builtin_amdgcn_mfma_f32_16x16x32_bf16(
                    afr[ks], Wlds[(ct * 8 + ks) * 64 + lane], acc, 0, 0, 0);
            }
            // D layout: row = quad*4 + i, col = lane&15
            size_t base = (size_t)(r0 + quad * 4) * 256 + h * 128 + ct * 16 + m;
            out[base]       = acc[0];
            out[base + 256] = acc[1];
            out[base + 512] = acc[2];
            out[base + 768] = acc[3];
        }
    }
}

extern "C" void kernel_launch(void* const* d_in, const int* in_sizes, int n_in,
                              void* d_out, int out_size, void* d_ws, size_t ws_size,
                              hipStream_t stream) {
    const float* x    = (const float*)d_in[0];   // [8,20000,256]
    const float* Wnl  = (const float*)d_in[1];   // [256,2]
    const float* bnl  = (const float*)d_in[2];   // [256]
    const float* Wout = (const float*)d_in[3];   // [256,256]
    const float* bout = (const float*)d_in[4];   // [256]

    unsigned short* wfrag = (unsigned short*)d_ws;            // 65536 bf16 = 128 KB
    float* wbias = (float*)((char*)d_ws + 131072);            // 256 f32

    wk_prep<<<257, 256, 0, stream>>>(Wnl, bnl, Wout, bout, wfrag, wbias);
    wk_main<<<1250, 512, 0, stream>>>(x, wfrag, wbias, (float*)d_out);
}